// Round 4
// baseline (829.400 us; speedup 1.0000x reference)
//
#include <hip/hip_runtime.h>
#include <hip/hip_bf16.h>
#include <stdint.h>

// NNUE bucket model R4: explicit LDS double-buffer in both GEMMs.
// R3 showed MfmaUtil 15% / VALU 14% / HBM 17% => latency-bound: the fused
// A-staging chain (fp32 load -> cvt -> ds_write -> vmcnt(0) -> barrier) was
// serialized with MFMA. Now: per iter, issue A(kt+1) reg loads + B(kt+1)
// gl_lds into buffer nxt, run MFMA(kt) on buffer cur (covers load latency),
// then cvt+ds_write A(kt+1), ONE barrier.
//   K2: convert ft_w -> (512,800) fp16 padded, h1_w -> (256,1024) fp16
//   K3: gemm_ft_fused: BM=128 BN=256 BK=32, 512 thr, dbuf 48 KB LDS
//   K4: gemm_h1: BM=64 BN=256(full), 512 thr, dbuf 40 KB LDS
//   K5: tail unchanged.
// LDS chunk-XOR swizzle throughout (R2: conflicts 1.3e7 -> 0).

#define INF  770
#define XROW 1540
#define KP   800
#define FT   512
#define K2   1024
#define N2   256

typedef _Float16 half8 __attribute__((ext_vector_type(8)));
typedef float floatx4 __attribute__((ext_vector_type(4)));
typedef float floatx2 __attribute__((ext_vector_type(2)));

__device__ __forceinline__ float crelu_f(float v) {
    return v < 0.f ? 0.f : (v > 1.f ? 1.f : v);
}

__device__ __forceinline__ void gl_lds16(const _Float16* g, _Float16* l) {
    __builtin_amdgcn_global_load_lds(
        (__attribute__((address_space(1))) void*)(uintptr_t)(const void*)g,
        (__attribute__((address_space(3))) void*)l,
        16, 0, 0);
}

// ---------------- K2: convert weights ----------------
__global__ __launch_bounds__(256) void convert_w_kernel(
    const float* __restrict__ ftw, const float* __restrict__ h1w,
    _Float16* __restrict__ ftw16, _Float16* __restrict__ h1w16)
{
    int idx = blockIdx.x * 256 + threadIdx.x;
    const int FTW = FT * KP;            // 409600
    if (idx < FTW) {
        int r = idx / KP, c = idx - r * KP;
        ftw16[idx] = (_Float16)(c < INF ? ftw[r * INF + c] : 0.f);
    } else {
        int j = idx - FTW;
        if (j < N2 * K2) h1w16[j] = (_Float16)h1w[j];
    }
}

// ---------------- K3: fused FT GEMM, double-buffered ----------------
__global__ __launch_bounds__(512, 4) void gemm_ft_fused(
    const float* __restrict__ x,      // (B, 1540)
    const _Float16* __restrict__ Bt,  // (512, 800) padded fp16
    const float* __restrict__ bias,   // (512)
    _Float16* __restrict__ C,         // (2B, 512)
    int* __restrict__ bucket, int B)
{
    __shared__ _Float16 lsA[2][128 * 32];   // 16 KB
    __shared__ _Float16 lsB[2][256 * 32];   // 32 KB
    int bid = blockIdx.x;
    int xcd = bid & 7, g = bid >> 3;
    int nt = g & 1, mt = (g >> 1) * 8 + xcd;      // mt in [0,1024)
    int m0 = mt * 128, n0 = nt * 256;
    int tid = threadIdx.x, lane = tid & 63, w = tid >> 6;
    int rm = (w & 1) * 64, rn = (w >> 1) * 64;
    int colL = lane & 15, rowQ = lane >> 4;
    int chA = rowQ ^ ((colL >> 1) & 3);

    // A staging identity: thread -> (row, 16B chunk kq)
    int arow = tid >> 2, kq = tid & 3;
    const float* asrc = (m0 < B)
        ? x + (size_t)(m0 + arow) * XROW
        : x + (size_t)(m0 - B + arow) * XROW + INF;
    int adoff = arow * 32 + (kq ^ ((arow >> 1) & 3)) * 8;

    // edge k-chunk (k=768,769) prefetched once
    floatx2 edge;
    if (kq == 0) edge = *(const floatx2*)(asrc + 768);

    floatx4 acc[4][4] = {};
    float psum = 0.f;

    // ---- prologue: stage iter 0 into buf 0 ----
    {
        const float* p = asrc + kq * 8;
        floatx4 f01 = *(const floatx4*)p;
        floatx4 f23 = *(const floatx4*)(p + 4);
        half8 hv;
        hv[0] = (_Float16)f01.x; hv[1] = (_Float16)f01.y;
        hv[2] = (_Float16)f01.z; hv[3] = (_Float16)f01.w;
        hv[4] = (_Float16)f23.x; hv[5] = (_Float16)f23.y;
        hv[6] = (_Float16)f23.z; hv[7] = (_Float16)f23.w;
        psum += (f01.x + f01.y) + (f01.z + f01.w) + (f23.x + f23.y) + (f23.z + f23.w);
        *(half8*)(lsA[0] + adoff) = hv;
        #pragma unroll
        for (int p2 = 0; p2 < 2; ++p2) {
            int idx = p2 * 512 + tid;
            int br = idx >> 2, bs = (idx & 3) ^ ((br >> 1) & 3);
            gl_lds16(Bt + (size_t)(n0 + br) * KP + bs * 8, lsB[0] + idx * 8);
        }
    }
    __syncthreads();

    for (int kt = 0; kt < 25; ++kt) {
        int cur = kt & 1, nxt = cur ^ 1;
        bool full = (kt + 1 < 24);     // next iter has all-real k
        // ---- issue next A loads (regs) + next B gl_lds into nxt ----
        floatx4 f01, f23;
        if (full) {
            const float* p = asrc + (kt + 1) * 32 + kq * 8;
            f01 = *(const floatx4*)p;
            f23 = *(const floatx4*)(p + 4);
        }
        if (kt + 1 < 25) {
            int ks = (kt + 1) * 32;
            #pragma unroll
            for (int p2 = 0; p2 < 2; ++p2) {
                int idx = p2 * 512 + tid;
                int br = idx >> 2, bs = (idx & 3) ^ ((br >> 1) & 3);
                gl_lds16(Bt + (size_t)(n0 + br) * KP + ks + bs * 8, lsB[nxt] + idx * 8);
            }
        }
        // ---- MFMA on cur (covers the load latency) ----
        half8 af[4], bf[4];
        #pragma unroll
        for (int i = 0; i < 4; ++i)
            af[i] = *(const half8*)(lsA[cur] + (rm + i * 16 + colL) * 32 + chA * 8);
        #pragma unroll
        for (int j = 0; j < 4; ++j)
            bf[j] = *(const half8*)(lsB[cur] + (rn + j * 16 + colL) * 32 + chA * 8);
        #pragma unroll
        for (int i = 0; i < 4; ++i)
            #pragma unroll
            for (int j = 0; j < 4; ++j)
                acc[i][j] = __builtin_amdgcn_mfma_f32_16x16x32_f16(af[i], bf[j], acc[i][j], 0, 0, 0);
        // ---- cvt + ds_write next A into nxt ----
        if (kt + 1 < 25) {
            half8 hv = {};
            if (full) {
                hv[0] = (_Float16)f01.x; hv[1] = (_Float16)f01.y;
                hv[2] = (_Float16)f01.z; hv[3] = (_Float16)f01.w;
                hv[4] = (_Float16)f23.x; hv[5] = (_Float16)f23.y;
                hv[6] = (_Float16)f23.z; hv[7] = (_Float16)f23.w;
                psum += (f01.x + f01.y) + (f01.z + f01.w) + (f23.x + f23.y) + (f23.z + f23.w);
            } else if (kq == 0) {
                hv[0] = (_Float16)edge.x; hv[1] = (_Float16)edge.y;
            }
            *(half8*)(lsA[nxt] + adoff) = hv;
        }
        __syncthreads();
    }

    // ---- bucket (pc = sum x[:, :768] = the 24 full iters) ----
    psum += __shfl_xor(psum, 1, 64);
    psum += __shfl_xor(psum, 2, 64);
    if (nt == 0 && m0 < B && (tid & 3) == 0) {
        int bk = (int)(psum * (8.0f / 33.0f));
        bucket[m0 + arow] = bk < 0 ? 0 : (bk > 7 ? 7 : bk);
    }

    // ---- epilogue ----
    #pragma unroll
    for (int j = 0; j < 4; ++j) {
        int gn = n0 + rn + j * 16 + colL;
        float bv = bias[gn];
        #pragma unroll
        for (int i = 0; i < 4; ++i) {
            #pragma unroll
            for (int r = 0; r < 4; ++r) {
                int gm = m0 + rm + i * 16 + rowQ * 4 + r;
                C[(size_t)gm * FT + gn] = (_Float16)crelu_f(acc[i][j][r] + bv);
            }
        }
    }
}

// ---------------- K4: h1 GEMM, double-buffered ----------------
__global__ __launch_bounds__(512, 4) void gemm_h1_kernel(
    const _Float16* __restrict__ C1,  // (2B, 512)
    const _Float16* __restrict__ Bt,  // (256, 1024)
    const float* __restrict__ bias,   // (256)
    float* __restrict__ H,            // (B, 256)
    int B)
{
    __shared__ _Float16 lsA[2][64 * 32];    // 8 KB
    __shared__ _Float16 lsB[2][256 * 32];   // 32 KB
    int m0 = blockIdx.x * 64;
    int tid = threadIdx.x, lane = tid & 63, w = tid >> 6;   // 8 waves: n-slice 32 each
    int colL = lane & 15, rowQ = lane >> 4;
    int chA = rowQ ^ ((colL >> 1) & 3);

    floatx4 acc[4][2] = {};

    // stage(kt, buf):
    //   combined[m][k] = k<512 ? C1[m][k] : C1[B+m][k-512]
    #define H1_STAGE(KT, BUF) do {                                              \
        int ks_ = (KT) * 32;                                                    \
        const _Float16* Abase_ = (ks_ < FT)                                     \
            ? (C1 + (size_t)m0 * FT + ks_)                                      \
            : (C1 + (size_t)(B + m0) * FT + (ks_ - FT));                        \
        if (tid < 256) {                                                        \
            int br_ = tid >> 2, bs_ = (tid & 3) ^ ((br_ >> 1) & 3);             \
            gl_lds16(Abase_ + (size_t)br_ * FT + bs_ * 8, lsA[BUF] + tid * 8);  \
        }                                                                       \
        _Pragma("unroll")                                                       \
        for (int p2_ = 0; p2_ < 2; ++p2_) {                                     \
            int idx_ = p2_ * 512 + tid;                                         \
            int br_ = idx_ >> 2, bs_ = (idx_ & 3) ^ ((br_ >> 1) & 3);           \
            gl_lds16(Bt + (size_t)br_ * K2 + ks_ + bs_ * 8, lsB[BUF] + idx_ * 8); \
        }                                                                       \
    } while (0)

    H1_STAGE(0, 0);
    __syncthreads();

    for (int kt = 0; kt < 32; ++kt) {
        int cur = kt & 1, nxt = cur ^ 1;
        if (kt + 1 < 32) H1_STAGE(kt + 1, nxt);
        half8 af[4], bf[2];
        #pragma unroll
        for (int i = 0; i < 4; ++i)
            af[i] = *(const half8*)(lsA[cur] + (i * 16 + colL) * 32 + chA * 8);
        #pragma unroll
        for (int j = 0; j < 2; ++j)
            bf[j] = *(const half8*)(lsB[cur] + (w * 32 + j * 16 + colL) * 32 + chA * 8);
        #pragma unroll
        for (int i = 0; i < 4; ++i)
            #pragma unroll
            for (int j = 0; j < 2; ++j)
                acc[i][j] = __builtin_amdgcn_mfma_f32_16x16x32_f16(af[i], bf[j], acc[i][j], 0, 0, 0);
        __syncthreads();
    }
    #undef H1_STAGE

    #pragma unroll
    for (int j = 0; j < 2; ++j) {
        int gn = w * 32 + j * 16 + colL;
        float bv = bias[gn];
        #pragma unroll
        for (int i = 0; i < 4; ++i) {
            #pragma unroll
            for (int r = 0; r < 4; ++r) {
                int gm = m0 + i * 16 + rowQ * 4 + r;
                H[(size_t)gm * N2 + gn] = crelu_f(acc[i][j][r] + bv);
            }
        }
    }
}

// ---------------- K5: tail (h2 + h3, bucket-selected) ----------------
__global__ __launch_bounds__(256) void tail_kernel(
    const float* __restrict__ H,
    const int* __restrict__ bucket,
    const float* __restrict__ h2w,     // (8,32,32)
    const float* __restrict__ h2b,     // (8,32)
    const float* __restrict__ h3w,     // (8,1,32)
    const float* __restrict__ h3b,     // (8,1)
    float* __restrict__ out, int B)
{
    int s = blockIdx.x * 8 + (threadIdx.x >> 5);
    int j = threadIdx.x & 31;
    if (s >= B) return;
    int k = bucket[s];
    float h1v = H[(size_t)s * N2 + k * 32 + j];
    const float* w2 = h2w + ((k * 32 + j) * 32);
    float a = h2b[k * 32 + j];
    #pragma unroll
    for (int i = 0; i < 32; ++i) a += w2[i] * __shfl(h1v, i, 32);
    a = crelu_f(a);
    float p = a * h3w[k * 32 + j];
    #pragma unroll
    for (int off = 16; off; off >>= 1) p += __shfl_down(p, off, 32);
    if (j == 0) out[s] = p + h3b[k];
}

extern "C" void kernel_launch(void* const* d_in, const int* in_sizes, int n_in,
                              void* d_out, int out_size, void* d_ws, size_t ws_size,
                              hipStream_t stream) {
    const float* x    = (const float*)d_in[0];
    const float* ftw  = (const float*)d_in[1];
    const float* ftb  = (const float*)d_in[2];
    const float* h1w  = (const float*)d_in[3];
    const float* h1b  = (const float*)d_in[4];
    const float* h2w  = (const float*)d_in[5];
    const float* h2b  = (const float*)d_in[6];
    const float* h3w  = (const float*)d_in[7];
    const float* h3b  = (const float*)d_in[8];
    float* out = (float*)d_out;

    int B = in_sizes[0] / (2 * INF);          // 65536

    // workspace layout
    char* ws = (char*)d_ws;
    _Float16* C1    = (_Float16*)ws;                          // 2B*512*2 = 134 MB
    size_t c1_b     = (size_t)2 * B * FT * sizeof(_Float16);
    _Float16* ftw16 = (_Float16*)(ws + c1_b);                 // 512*800*2
    size_t ftw_b    = (size_t)FT * KP * sizeof(_Float16);
    _Float16* h1w16 = (_Float16*)(ws + c1_b + ftw_b);         // 256*1024*2
    size_t h1w_b    = (size_t)N2 * K2 * sizeof(_Float16);
    int* bucket     = (int*)(ws + c1_b + ftw_b + h1w_b);      // B*4
    size_t bk_b     = (size_t)B * sizeof(int);
    float* H        = (float*)(ws + c1_b + ftw_b + h1w_b + bk_b); // B*256*4

    // K2: weights
    {
        int total = FT * KP + N2 * K2;
        convert_w_kernel<<<(total + 255) / 256, 256, 0, stream>>>(ftw, h1w, ftw16, h1w16);
    }
    // K3: fused FT GEMM (+bucket)
    gemm_ft_fused<<<(2 * B / 128) * 2, 512, 0, stream>>>(x, ftw16, ftb, C1, bucket, B);
    // K4: h1 GEMM
    gemm_h1_kernel<<<B / 64, 512, 0, stream>>>(C1, h1w16, h1b, H, B);
    // K5: tail
    tail_kernel<<<(B + 7) / 8, 256, 0, stream>>>(H, bucket, h2w, h2b, h3w, h3b, out, B);
}